// Round 6
// baseline (146.335 us; speedup 1.0000x reference)
//
#include <hip/hip_runtime.h>

#define BN   8192
#define DIM  128
#define NCLS 128
#define NBLK 4096         // 128 i-strips x 32 j-splits, 1 wave each

typedef __attribute__((ext_vector_type(8))) short bf16x8;   // 8 x bf16 = 4 VGPRs
typedef __attribute__((ext_vector_type(4))) float f32x4;

// round-to-nearest-even f32 -> bf16
static __device__ __forceinline__ unsigned short f2bf(float x) {
    union { float f; unsigned u; } c; c.f = x;
    unsigned r = c.u + 0x7FFFu + ((c.u >> 16) & 1u);
    return (unsigned short)(r >> 16);
}

static __device__ __forceinline__ bf16x8 ldb8(const unsigned short* p) {
    return *reinterpret_cast<const bf16x8*>(p);
}

// monotone float<->uint key: enc(a) < enc(b)  <=>  a < b
static __device__ __forceinline__ unsigned encf(float f) {
    unsigned u = __float_as_uint(f);
    return (u >> 31) ? ~u : (u | 0x80000000u);
}
static __device__ __forceinline__ float decf(unsigned v) {
    return __uint_as_float((v >> 31) ? (v & 0x7FFFFFFFu) : ~v);
}

// ---------------- S1: fused sort (block-per-class) + normalize + init -------
// Block c: counts labels<c (class offset) and collects its rows in a fixed
// deterministic order, then normalizes and scatters bf16 rows into sorted
// positions. Also resets the done counter used by tri_main's folded finalize.
__global__ __launch_bounds__(256) void sort_norm(const float* __restrict__ emb,
                                                 const int* __restrict__ labels,
                                                 unsigned short* __restrict__ ebf,
                                                 int2* __restrict__ se,
                                                 unsigned* __restrict__ hp2,
                                                 unsigned* __restrict__ hn2,
                                                 int* __restrict__ done) {
    const int c   = blockIdx.x;              // class id
    const int tid = threadIdx.x;
    if (c == 0 && tid == 0) *done = 0;       // reset last-block counter each call
    __shared__ int sl[256], so[256];
    __shared__ int srcrow[512];              // class size guard (E=64, sd~8)

    int nl = 0, no = 0;
#pragma unroll 8
    for (int k = 0; k < 32; ++k) {           // coalesced label reads
        int lb = labels[k * 256 + tid];
        nl += (lb < c);
        no += (lb == c);
    }
    sl[tid] = nl; so[tid] = no;
    __syncthreads();
    for (int off = 1; off < 256; off <<= 1) {   // Hillis-Steele inclusive scan
        int a1 = 0, a2 = 0;
        if (tid >= off) { a1 = sl[tid - off]; a2 = so[tid - off]; }
        __syncthreads();
        sl[tid] += a1; so[tid] += a2;
        __syncthreads();
    }
    const int offs_c = sl[255];              // rows with label < c
    const int n_c    = so[255];              // class size
    int mypos = so[tid] - no;                // exclusive prefix of own-count
    for (int k = 0; k < 32; ++k) {           // deterministic placement
        int r = k * 256 + tid;
        if (labels[r] == c) srcrow[mypos++] = r;
    }
    __syncthreads();

    const int wave = tid >> 6, lane = tid & 63;
    for (int k = wave; k < n_c; k += 4) {
        int r   = srcrow[k];
        int pos = offs_c + k;
        float2 v = reinterpret_cast<const float2*>(emb + (size_t)r * DIM)[lane];
        float ss = v.x * v.x + v.y * v.y;
#pragma unroll
        for (int m = 1; m < 64; m <<= 1) ss += __shfl_xor(ss, m);
        float inv = 1.0f / fmaxf(sqrtf(ss), 1e-12f);
        ushort2 bv; bv.x = f2bf(v.x * inv); bv.y = f2bf(v.y * inv);
        reinterpret_cast<ushort2*>(ebf + (size_t)pos * DIM)[lane] = bv;
        if (lane == 0) {
            se[pos]  = make_int2(offs_c, offs_c + n_c);
            hp2[pos] = 0xFFFFFFFFu;          // min-key identity
            hn2[pos] = 0u;                   // max-key identity
        }
    }
}

// --------------------------------- main -------------------------------------
// 4096 independent 1-WAVE blocks: 128 i-strips (64 sorted rows, A panel in
// 64 VGPRs) x 32 j-splits (256 cols = 16 tiles of 16). NO barriers, NO LDS:
// latency is hidden by ~12 independent waves/CU at different phases (TLP),
// plus depth-1 register prefetch of the next B tile.
// Tracks DOT products: hardest_pos = min dot over same-class (self included,
// self-dot~1 never wins the min), hardest_neg = max dot over rest. Sorted
// labels => pos columns contiguous [s,e); tiles outside the strip window
// [w0,w1) are wave-uniformly pure-negative -> 1 v_max per acc element.
// Last block to finish folds the finalize reduction (done-counter handshake).
__global__ __launch_bounds__(64) void tri_main(const unsigned short* __restrict__ ebf,
                                               const int2* __restrict__ se,
                                               unsigned* __restrict__ hp2,
                                               unsigned* __restrict__ hn2,
                                               int* __restrict__ done,
                                               float* __restrict__ out) {
    const int lane = threadIdx.x;
    const int lr   = lane & 15;        // A row / B col / C col within 16x16 tile
    const int lk   = lane >> 4;        // k-group
    const int iblk = blockIdx.x >> 5;
    const int jsp  = blockIdx.x & 31;
    const int i0    = iblk * 64;
    const int jbase = jsp * 256;

    // A panel: 4 x 16-row subtiles, K=128 (64 VGPRs, loaded once, L2-hit)
    bf16x8 a[4][4];
#pragma unroll
    for (int t = 0; t < 4; ++t) {
        const unsigned short* ar = ebf + (size_t)(i0 + t * 16 + lr) * DIM + lk * 8;
#pragma unroll
        for (int kk = 0; kk < 4; ++kk) a[t][kk] = ldb8(ar + kk * 32);
    }

    // strip window: union of class ranges of rows i0..i0+63 (sorted => contiguous)
    const int w0 = __builtin_amdgcn_readfirstlane(se[i0].x);
    const int w1 = __builtin_amdgcn_readfirstlane(se[i0 + 63].y);

    float hp[4][4], hn[4][4];                // dot-space: min-pos / max-neg
#pragma unroll
    for (int t = 0; t < 4; ++t)
#pragma unroll
        for (int m = 0; m < 4; ++m) { hp[t][m] = 1e30f; hn[t][m] = -1e30f; }

    const unsigned short* bp = ebf + (size_t)(jbase + lr) * DIM + lk * 8;

    // depth-1 register prefetch
    bf16x8 nb0 = ldb8(bp), nb1 = ldb8(bp + 32), nb2 = ldb8(bp + 64), nb3 = ldb8(bp + 96);

    for (int jt = 0; jt < 16; ++jt) {
        bf16x8 b0 = nb0, b1 = nb1, b2 = nb2, b3 = nb3;
        if (jt < 15) {
            const unsigned short* q = bp + (size_t)(jt + 1) * 16 * DIM;
            nb0 = ldb8(q); nb1 = ldb8(q + 32); nb2 = ldb8(q + 64); nb3 = ldb8(q + 96);
        }
        const int j0 = jbase + jt * 16;
        if (j0 + 16 <= w0 || j0 >= w1) {     // pure-negative tile (common fast path)
#pragma unroll
            for (int t = 0; t < 4; ++t) {
                f32x4 c4 = {0.f, 0.f, 0.f, 0.f};
                c4 = __builtin_amdgcn_mfma_f32_16x16x32_bf16(a[t][0], b0, c4, 0, 0, 0);
                c4 = __builtin_amdgcn_mfma_f32_16x16x32_bf16(a[t][1], b1, c4, 0, 0, 0);
                c4 = __builtin_amdgcn_mfma_f32_16x16x32_bf16(a[t][2], b2, c4, 0, 0, 0);
                c4 = __builtin_amdgcn_mfma_f32_16x16x32_bf16(a[t][3], b3, c4, 0, 0, 0);
#pragma unroll
                for (int m = 0; m < 4; ++m) hn[t][m] = fmaxf(hn[t][m], c4[m]);
            }
        } else {                             // mixed tile (rare, near diagonal)
            const int jc = j0 + lr;
#pragma unroll
            for (int t = 0; t < 4; ++t) {
                f32x4 c4 = {0.f, 0.f, 0.f, 0.f};
                c4 = __builtin_amdgcn_mfma_f32_16x16x32_bf16(a[t][0], b0, c4, 0, 0, 0);
                c4 = __builtin_amdgcn_mfma_f32_16x16x32_bf16(a[t][1], b1, c4, 0, 0, 0);
                c4 = __builtin_amdgcn_mfma_f32_16x16x32_bf16(a[t][2], b2, c4, 0, 0, 0);
                c4 = __builtin_amdgcn_mfma_f32_16x16x32_bf16(a[t][3], b3, c4, 0, 0, 0);
#pragma unroll
                for (int m = 0; m < 4; ++m) {
                    // volatile: keep these rare-path loads inside the branch
                    volatile const int2* vq = &se[i0 + t * 16 + lk * 4 + m];
                    int qs = vq->x, qe = vq->y;
                    bool pos = (jc >= qs) && (jc < qe);
                    hp[t][m] = pos ? fminf(hp[t][m], c4[m]) : hp[t][m];
                    hn[t][m] = pos ? hn[t][m] : fmaxf(hn[t][m], c4[m]);
                }
            }
        }
    }

    // reduce across the 16 lanes (lr) sharing accum rows, then global atomics
#pragma unroll
    for (int t = 0; t < 4; ++t)
#pragma unroll
        for (int m = 0; m < 4; ++m) {
            float p = hp[t][m], n = hn[t][m];
#pragma unroll
            for (int s = 1; s < 16; s <<= 1) {
                p = fminf(p, __shfl_xor(p, s));
                n = fmaxf(n, __shfl_xor(n, s));
            }
            if (lr == 0) {
                int r = i0 + t * 16 + lk * 4 + m;
                atomicMin(&hp2[r], encf(p));
                atomicMax(&hn2[r], encf(n));
            }
        }

    // ---- folded finalize: last block to arrive reduces hp2/hn2 -> out[0] ----
    int lastf = 0;
    if (lane == 0) {
        __threadfence();                     // release our atomics
        lastf = (atomicAdd(done, 1) == NBLK - 1);
    }
    lastf = __shfl(lastf, 0);
    if (!lastf) return;
    __threadfence();                         // acquire all blocks' atomics

    float sum = 0.f;
#pragma unroll 4
    for (int it = 0; it < BN / (64 * 4); ++it) {     // 32 iters, 4 rows/lane each
        int base = (it * 64 + lane) * 4;
        uint4 pv = *reinterpret_cast<const uint4*>(&hp2[base]);
        uint4 nv = *reinterpret_cast<const uint4*>(&hn2[base]);
        unsigned pa[4] = {pv.x, pv.y, pv.z, pv.w};
        unsigned na[4] = {nv.x, nv.y, nv.z, nv.w};
#pragma unroll
        for (int e = 0; e < 4; ++e) {
            float pd = decf(pa[e]);          // min dot over pos
            float nd = decf(na[e]);          // max dot over neg
            float hpv = sqrtf(fmaxf(2.0f - 2.0f * pd, 0.f));
            float hnv = sqrtf(fmaxf(2.0f - 2.0f * nd, 0.f));
            // relu(hp - hn + 0.5*(1+hp)) = relu(1.5*hp + 0.5 - hn)
            sum += fmaxf(fmaf(1.5f, hpv, 0.5f) - hnv, 0.f);
        }
    }
#pragma unroll
    for (int s = 1; s < 64; s <<= 1) sum += __shfl_xor(sum, s);
    if (lane == 0) out[0] = sum * (1.0f / (float)BN);    // all rows valid
}

// ---------------------------------------------------------------- launch
extern "C" void kernel_launch(void* const* d_in, const int* in_sizes, int n_in,
                              void* d_out, int out_size, void* d_ws, size_t ws_size,
                              hipStream_t stream) {
    const float* emb    = (const float*)d_in[0];
    const int*   labels = (const int*)d_in[1];
    float* out = (float*)d_out;

    char* ws = (char*)d_ws;
    unsigned short* ebf = (unsigned short*)ws;                            // 2 MiB sorted bf16 E
    int2*     se   = (int2*)    (ws + 2u * 1024u * 1024u);                // 64 KiB class ranges
    unsigned* hp2  = (unsigned*)(ws + 2u * 1024u * 1024u + 64u * 1024u);  // 32 KiB
    unsigned* hn2  = (unsigned*)(ws + 2u * 1024u * 1024u + 96u * 1024u);  // 32 KiB
    int*      done = (int*)     (ws + 2u * 1024u * 1024u + 128u * 1024u); // 4 B

    hipLaunchKernelGGL(sort_norm, dim3(NCLS), dim3(256), 0, stream, emb, labels, ebf, se, hp2, hn2, done);
    hipLaunchKernelGGL(tri_main,  dim3(NBLK), dim3(64),  0, stream, ebf, se, hp2, hn2, done, out);
}

// Round 7
// 85.468 us; speedup vs baseline: 1.7122x; 1.7122x over previous
//
#include <hip/hip_runtime.h>

#define BN   8192
#define DIM  128
#define NCLS 128
#define NBLK 1024         // 128 i-strips x 8 j-splits, 4 independent waves each

typedef __attribute__((ext_vector_type(8))) short bf16x8;   // 8 x bf16 = 4 VGPRs
typedef __attribute__((ext_vector_type(4))) float f32x4;

// round-to-nearest-even f32 -> bf16
static __device__ __forceinline__ unsigned short f2bf(float x) {
    union { float f; unsigned u; } c; c.f = x;
    unsigned r = c.u + 0x7FFFu + ((c.u >> 16) & 1u);
    return (unsigned short)(r >> 16);
}

static __device__ __forceinline__ bf16x8 ldb8(const unsigned short* p) {
    return *reinterpret_cast<const bf16x8*>(p);
}

// monotone float<->uint key: enc(a) < enc(b)  <=>  a < b
static __device__ __forceinline__ unsigned encf(float f) {
    unsigned u = __float_as_uint(f);
    return (u >> 31) ? ~u : (u | 0x80000000u);
}
static __device__ __forceinline__ float decf(unsigned v) {
    return __uint_as_float((v >> 31) ? (v & 0x7FFFFFFFu) : ~v);
}

// ---------------- S1: fused sort (block-per-class) + normalize + init -------
// Block c: counts labels<c (class offset), collects its rows deterministically,
// normalizes and scatters bf16 rows into sorted positions. Resets done counter.
__global__ __launch_bounds__(256) void sort_norm(const float* __restrict__ emb,
                                                 const int* __restrict__ labels,
                                                 unsigned short* __restrict__ ebf,
                                                 int2* __restrict__ se,
                                                 unsigned* __restrict__ hp2,
                                                 unsigned* __restrict__ hn2,
                                                 int* __restrict__ done) {
    const int c   = blockIdx.x;              // class id
    const int tid = threadIdx.x;
    if (c == 0 && tid == 0) *done = 0;       // reset last-block counter each call
    __shared__ int sl[256], so[256];
    __shared__ int srcrow[512];              // class size guard (E=64, sd~8)

    int nl = 0, no = 0;
#pragma unroll 8
    for (int k = 0; k < 32; ++k) {           // coalesced label reads
        int lb = labels[k * 256 + tid];
        nl += (lb < c);
        no += (lb == c);
    }
    sl[tid] = nl; so[tid] = no;
    __syncthreads();
    for (int off = 1; off < 256; off <<= 1) {   // Hillis-Steele inclusive scan
        int a1 = 0, a2 = 0;
        if (tid >= off) { a1 = sl[tid - off]; a2 = so[tid - off]; }
        __syncthreads();
        sl[tid] += a1; so[tid] += a2;
        __syncthreads();
    }
    const int offs_c = sl[255];              // rows with label < c
    const int n_c    = so[255];              // class size
    int mypos = so[tid] - no;                // exclusive prefix of own-count
    for (int k = 0; k < 32; ++k) {           // deterministic placement
        int r = k * 256 + tid;
        if (labels[r] == c) srcrow[mypos++] = r;
    }
    __syncthreads();

    const int wave = tid >> 6, lane = tid & 63;
    for (int k = wave; k < n_c; k += 4) {
        int r   = srcrow[k];
        int pos = offs_c + k;
        float2 v = reinterpret_cast<const float2*>(emb + (size_t)r * DIM)[lane];
        float ss = v.x * v.x + v.y * v.y;
#pragma unroll
        for (int m = 1; m < 64; m <<= 1) ss += __shfl_xor(ss, m);
        float inv = 1.0f / fmaxf(sqrtf(ss), 1e-12f);
        ushort2 bv; bv.x = f2bf(v.x * inv); bv.y = f2bf(v.y * inv);
        reinterpret_cast<ushort2*>(ebf + (size_t)pos * DIM)[lane] = bv;
        if (lane == 0) {
            se[pos]  = make_int2(offs_c, offs_c + n_c);
            hp2[pos] = 0xFFFFFFFFu;          // min-key identity
            hn2[pos] = 0u;                   // max-key identity
        }
    }
}

// --------------------------------- main -------------------------------------
// 1024 blocks = 128 i-strips (64 sorted rows) x 8 j-splits; 4 INDEPENDENT
// waves (no barrier until the final reduce). __launch_bounds__(256,2) caps at
// 256 VGPR so the allocator keeps the pipeline live (~185 regs) instead of
// sinking the prefetch to fit 4 waves/SIMD (the R1-R6 pathology, VGPR~112).
// Manual ping-pong depth-1 pipeline with NAMED register sets: each tile's B
// loads are issued before the previous tile's branchy epilogue, so L2 latency
// (~225cy) hides under the 16-MFMA chain (~310cy) even at 2 waves/SIMD.
// Tracks DOT products: hardest_pos = min dot over same-class (self included,
// self-dot~1 never wins the min), hardest_neg = max dot over rest. Sorted
// labels => pos cols contiguous [st,en); tiles outside the strip window
// [w0,w1) are wave-uniformly pure-negative -> 1 v_max per acc element.
__global__ __launch_bounds__(256, 2) void tri_main(const unsigned short* __restrict__ ebf,
                                                   const int2* __restrict__ se,
                                                   unsigned* __restrict__ hp2,
                                                   unsigned* __restrict__ hn2,
                                                   int* __restrict__ done,
                                                   float* __restrict__ out) {
    __shared__ float hpL[4][64], hnL[4][64];
    __shared__ int amlast;

    const int tid  = threadIdx.x;
    const int wave = tid >> 6;
    const int lane = tid & 63;
    const int lr   = lane & 15;        // A row / B col / C col within 16x16 tile
    const int lk   = lane >> 4;        // k-group
    const int iblk  = blockIdx.x >> 3;
    const int jsp   = blockIdx.x & 7;
    const int i0    = iblk * 64;
    const int jbase = jsp * 1024 + wave * 256;   // this wave's 256-col slice

    // A panel: 4 x 16-row subtiles, K=128 (64 VGPRs, loaded once, L2-hit)
    bf16x8 a[4][4];
#pragma unroll
    for (int t = 0; t < 4; ++t) {
        const unsigned short* ar = ebf + (size_t)(i0 + t * 16 + lr) * DIM + lk * 8;
#pragma unroll
        for (int kk = 0; kk < 4; ++kk) a[t][kk] = ldb8(ar + kk * 32);
    }

    // strip window: union of class ranges of rows i0..i0+63 (sorted => contiguous)
    const int w0 = __builtin_amdgcn_readfirstlane(se[i0].x);
    const int w1 = __builtin_amdgcn_readfirstlane(se[i0 + 63].y);

    // per-acc-row class range, packed (start<<16 | len)
    int sepk[4][4];
#pragma unroll
    for (int t = 0; t < 4; ++t)
#pragma unroll
        for (int m = 0; m < 4; ++m) {
            int2 q = se[i0 + t * 16 + lk * 4 + m];
            sepk[t][m] = (q.x << 16) | (q.y - q.x);
        }

    float hp[4][4], hn[4][4];                // dot-space: min-pos / max-neg
#pragma unroll
    for (int t = 0; t < 4; ++t)
#pragma unroll
        for (int m = 0; m < 4; ++m) { hp[t][m] = 1e30f; hn[t][m] = -1e30f; }

    const unsigned short* bp = ebf + (size_t)(jbase + lr) * DIM + lk * 8;

    // one tile's MFMA + epilogue (branch is wave-uniform; loads for the NEXT
    // tile are already in flight when we enter it)
    auto COMPUTE = [&](int j0, bf16x8 b0, bf16x8 b1, bf16x8 b2, bf16x8 b3) {
        f32x4 acc[4];
#pragma unroll
        for (int t = 0; t < 4; ++t) {
            f32x4 c4 = {0.f, 0.f, 0.f, 0.f};
            c4 = __builtin_amdgcn_mfma_f32_16x16x32_bf16(a[t][0], b0, c4, 0, 0, 0);
            c4 = __builtin_amdgcn_mfma_f32_16x16x32_bf16(a[t][1], b1, c4, 0, 0, 0);
            c4 = __builtin_amdgcn_mfma_f32_16x16x32_bf16(a[t][2], b2, c4, 0, 0, 0);
            c4 = __builtin_amdgcn_mfma_f32_16x16x32_bf16(a[t][3], b3, c4, 0, 0, 0);
            acc[t] = c4;
        }
        if (j0 + 16 <= w0 || j0 >= w1) {     // pure-negative tile (common)
#pragma unroll
            for (int t = 0; t < 4; ++t)
#pragma unroll
                for (int m = 0; m < 4; ++m) hn[t][m] = fmaxf(hn[t][m], acc[t][m]);
        } else {                             // mixed tile (near diagonal, rare)
            const int jc = j0 + lr;
#pragma unroll
            for (int t = 0; t < 4; ++t)
#pragma unroll
                for (int m = 0; m < 4; ++m) {
                    int  st  = sepk[t][m] >> 16;
                    int  len = sepk[t][m] & 0xFFFF;
                    bool pos = (unsigned)(jc - st) < (unsigned)len;
                    hp[t][m] = pos ? fminf(hp[t][m], acc[t][m]) : hp[t][m];
                    hn[t][m] = pos ? hn[t][m] : fmaxf(hn[t][m], acc[t][m]);
                }
        }
    };

    // ping-pong pipeline over 16 tiles (8 pairs), named register sets
    bf16x8 c0 = ldb8(bp), c1 = ldb8(bp + 32), c2 = ldb8(bp + 64), c3 = ldb8(bp + 96);
    for (int p = 0; p < 8; ++p) {
        const int t0 = p * 2;
        {   // issue loads for tile t0+1, then compute t0 (loads fly under MFMAs)
            const unsigned short* q = bp + (size_t)(t0 + 1) * 16 * DIM;
            bf16x8 n0 = ldb8(q), n1 = ldb8(q + 32), n2 = ldb8(q + 64), n3 = ldb8(q + 96);
            COMPUTE(jbase + t0 * 16, c0, c1, c2, c3);
            if (p < 7) {   // issue loads for tile t0+2, then compute t0+1
                const unsigned short* q2 = bp + (size_t)(t0 + 2) * 16 * DIM;
                c0 = ldb8(q2); c1 = ldb8(q2 + 32); c2 = ldb8(q2 + 64); c3 = ldb8(q2 + 96);
            }
            COMPUTE(jbase + (t0 + 1) * 16, n0, n1, n2, n3);
        }
    }

    // reduce across the 16 lanes sharing accum rows, then across waves in LDS
#pragma unroll
    for (int t = 0; t < 4; ++t)
#pragma unroll
        for (int m = 0; m < 4; ++m) {
            float p = hp[t][m], n = hn[t][m];
#pragma unroll
            for (int s = 1; s < 16; s <<= 1) {
                p = fminf(p, __shfl_xor(p, s));
                n = fmaxf(n, __shfl_xor(n, s));
            }
            if (lr == 0) {
                int r = t * 16 + lk * 4 + m;
                hpL[wave][r] = p;
                hnL[wave][r] = n;
            }
        }
    __syncthreads();
    if (tid < 64) {
        float p = fminf(fminf(hpL[0][tid], hpL[1][tid]), fminf(hpL[2][tid], hpL[3][tid]));
        float n = fmaxf(fmaxf(hnL[0][tid], hnL[1][tid]), fmaxf(hnL[2][tid], hnL[3][tid]));
        atomicMin(&hp2[i0 + tid], encf(p));
        atomicMax(&hn2[i0 + tid], encf(n));
    }
    __syncthreads();                         // all this block's atomics performed

    // ---- folded finalize: last block to arrive reduces hp2/hn2 -> out[0] ----
    if (tid == 0) {
        __threadfence();                     // release our atomics
        amlast = (atomicAdd(done, 1) == NBLK - 1);
    }
    __syncthreads();
    if (!amlast) return;
    __threadfence();                         // acquire all blocks' atomics

    float sum = 0.f;
#pragma unroll
    for (int it = 0; it < BN / (256 * 4); ++it) {    // 8 iters, uint4 per thread
        int base = (it * 256 + tid) * 4;
        uint4 pv = *reinterpret_cast<const uint4*>(&hp2[base]);
        uint4 nv = *reinterpret_cast<const uint4*>(&hn2[base]);
        unsigned pa[4] = {pv.x, pv.y, pv.z, pv.w};
        unsigned na[4] = {nv.x, nv.y, nv.z, nv.w};
#pragma unroll
        for (int e = 0; e < 4; ++e) {
            float pd = decf(pa[e]);          // min dot over pos
            float nd = decf(na[e]);          // max dot over neg
            float hpv = sqrtf(fmaxf(2.0f - 2.0f * pd, 0.f));
            float hnv = sqrtf(fmaxf(2.0f - 2.0f * nd, 0.f));
            // relu(hp - hn + 0.5*(1+hp)) = relu(1.5*hp + 0.5 - hn)
            sum += fmaxf(fmaf(1.5f, hpv, 0.5f) - hnv, 0.f);
        }
    }
    float* red = &hpL[0][0];                 // reuse 256 floats of LDS
    red[tid] = sum;
    __syncthreads();
    for (int s2 = 128; s2 > 0; s2 >>= 1) {
        if (tid < s2) red[tid] += red[tid + s2];
        __syncthreads();
    }
    if (tid == 0) out[0] = red[0] * (1.0f / (float)BN);    // all rows valid
}

// ---------------------------------------------------------------- launch
extern "C" void kernel_launch(void* const* d_in, const int* in_sizes, int n_in,
                              void* d_out, int out_size, void* d_ws, size_t ws_size,
                              hipStream_t stream) {
    const float* emb    = (const float*)d_in[0];
    const int*   labels = (const int*)d_in[1];
    float* out = (float*)d_out;

    char* ws = (char*)d_ws;
    unsigned short* ebf = (unsigned short*)ws;                            // 2 MiB sorted bf16 E
    int2*     se   = (int2*)    (ws + 2u * 1024u * 1024u);                // 64 KiB class ranges
    unsigned* hp2  = (unsigned*)(ws + 2u * 1024u * 1024u + 64u * 1024u);  // 32 KiB
    unsigned* hn2  = (unsigned*)(ws + 2u * 1024u * 1024u + 96u * 1024u);  // 32 KiB
    int*      done = (int*)     (ws + 2u * 1024u * 1024u + 128u * 1024u); // 4 B

    hipLaunchKernelGGL(sort_norm, dim3(NCLS), dim3(256), 0, stream, emb, labels, ebf, se, hp2, hn2, done);
    hipLaunchKernelGGL(tri_main,  dim3(NBLK), dim3(256), 0, stream, ebf, se, hp2, hn2, done, out);
}

// Round 8
// 67.723 us; speedup vs baseline: 2.1608x; 1.2620x over previous
//
#include <hip/hip_runtime.h>

#define BN   8192
#define DIM  128
#define NCLS 128
#define NBLK 512          // 64 i-tiles (128 rows) x 8 j-splits (1024 cols)
#define NST  8            // 8 stages of 128 cols per block

typedef __attribute__((ext_vector_type(8))) short bf16x8;   // 8 x bf16 = 4 VGPRs
typedef __attribute__((ext_vector_type(4))) float f32x4;

// round-to-nearest-even f32 -> bf16
static __device__ __forceinline__ unsigned short f2bf(float x) {
    union { float f; unsigned u; } c; c.f = x;
    unsigned r = c.u + 0x7FFFu + ((c.u >> 16) & 1u);
    return (unsigned short)(r >> 16);
}

static __device__ __forceinline__ bf16x8 ldb8(const unsigned short* p) {
    return *reinterpret_cast<const bf16x8*>(p);
}

// monotone float<->uint key: enc(a) < enc(b)  <=>  a < b
static __device__ __forceinline__ unsigned encf(float f) {
    unsigned u = __float_as_uint(f);
    return (u >> 31) ? ~u : (u | 0x80000000u);
}
static __device__ __forceinline__ float decf(unsigned v) {
    return __uint_as_float((v >> 31) ? (v & 0x7FFFFFFFu) : ~v);
}

// async global->LDS, 16B/lane; LDS dest wave-uniform base + lane*16
static __device__ __forceinline__ void gload_lds16(const unsigned short* g, unsigned short* l) {
    __builtin_amdgcn_global_load_lds(
        (const __attribute__((address_space(1))) unsigned int*)g,
        (__attribute__((address_space(3))) unsigned int*)l, 16, 0, 0);
}

// ---------------- S1: fused sort (block-per-class) + normalize + init -------
__global__ __launch_bounds__(256) void sort_norm(const float* __restrict__ emb,
                                                 const int* __restrict__ labels,
                                                 unsigned short* __restrict__ ebf,
                                                 int2* __restrict__ se,
                                                 unsigned* __restrict__ hp2,
                                                 unsigned* __restrict__ hn2,
                                                 int* __restrict__ done) {
    const int c   = blockIdx.x;              // class id
    const int tid = threadIdx.x;
    if (c == 0 && tid == 0) *done = 0;       // reset last-block counter each call
    __shared__ int sl[256], so[256];
    __shared__ int srcrow[512];              // class size guard (E=64, sd~8)

    int nl = 0, no = 0;
#pragma unroll 8
    for (int k = 0; k < 32; ++k) {           // coalesced label reads
        int lb = labels[k * 256 + tid];
        nl += (lb < c);
        no += (lb == c);
    }
    sl[tid] = nl; so[tid] = no;
    __syncthreads();
    for (int off = 1; off < 256; off <<= 1) {   // Hillis-Steele inclusive scan
        int a1 = 0, a2 = 0;
        if (tid >= off) { a1 = sl[tid - off]; a2 = so[tid - off]; }
        __syncthreads();
        sl[tid] += a1; so[tid] += a2;
        __syncthreads();
    }
    const int offs_c = sl[255];              // rows with label < c
    const int n_c    = so[255];              // class size
    int mypos = so[tid] - no;                // exclusive prefix of own-count
    for (int k = 0; k < 32; ++k) {           // deterministic placement
        int r = k * 256 + tid;
        if (labels[r] == c) srcrow[mypos++] = r;
    }
    __syncthreads();

    const int wave = tid >> 6, lane = tid & 63;
    for (int k = wave; k < n_c; k += 4) {
        int r   = srcrow[k];
        int pos = offs_c + k;
        float2 v = reinterpret_cast<const float2*>(emb + (size_t)r * DIM)[lane];
        float ss = v.x * v.x + v.y * v.y;
#pragma unroll
        for (int m = 1; m < 64; m <<= 1) ss += __shfl_xor(ss, m);
        float inv = 1.0f / fmaxf(sqrtf(ss), 1e-12f);
        ushort2 bv; bv.x = f2bf(v.x * inv); bv.y = f2bf(v.y * inv);
        reinterpret_cast<ushort2*>(ebf + (size_t)pos * DIM)[lane] = bv;
        if (lane == 0) {
            se[pos]  = make_int2(offs_c, offs_c + n_c);
            hp2[pos] = 0xFFFFFFFFu;          // min-key identity
            hn2[pos] = 0u;                   // max-key identity
        }
    }
}

// --------------------------------- main -------------------------------------
// 512 blocks = 64 i-tiles (128 sorted rows) x 8 j-splits (1024 cols); exactly
// 2 blocks/CU resident (LDS 66KB, ~190 VGPR). 4 waves in 2x2: wave (wr,wc)
// computes a 64x64 output tile per stage (4x4 fragments, 64 MFMA) -- 4x more
// compute per stall window than R1-R7's 16-col tiles, the knob never tried.
// B staged once per block per stage (32KB, shared by waves, double-buffered,
// counted vmcnt(8) + raw s_barrier so the next stage's loads stay in flight).
// XOR swizzle (source-chunk ^ col&7, same XOR on ds_read) -> conflict-free.
// Tracks DOT products: hardest_pos = min dot over same-class (self included,
// self-dot~1 never wins the min), hardest_neg = max dot over rest.
__global__ __launch_bounds__(256) void tri_main(const unsigned short* __restrict__ ebf,
                                                const int2* __restrict__ se,
                                                unsigned* __restrict__ hp2,
                                                unsigned* __restrict__ hn2,
                                                int* __restrict__ done,
                                                float* __restrict__ out) {
    __shared__ unsigned short bs[2][128 * DIM];   // 2 x 32 KiB B stages
    __shared__ float hpL[4][64], hnL[4][64];
    __shared__ int amlast;

    const int tid  = threadIdx.x;
    const int wave = tid >> 6;
    const int lane = tid & 63;
    const int lr   = lane & 15;        // fragment row/col within 16x16 tile
    const int lk   = lane >> 4;        // k-group
    const int wr   = wave >> 1;        // wave row (0..1): rows wr*64..wr*64+63
    const int wc   = wave & 1;         // wave col (0..1): cols wc*64..wc*64+63
    const int iblk  = blockIdx.x >> 3;
    const int jsp   = blockIdx.x & 7;  // == XCD id under round-robin dispatch
    const int i0    = iblk * 128;
    const int jbase = jsp * 1024;

    // A panel: this wave's 64 rows x K=128 (64 VGPRs, loaded once, issued FIRST
    // so the compiler's wait for their first use counts past the stage loads)
    bf16x8 a[4][4];
#pragma unroll
    for (int t = 0; t < 4; ++t) {
        const unsigned short* ar = ebf + (size_t)(i0 + wr * 64 + t * 16 + lr) * DIM + lk * 8;
#pragma unroll
        for (int kk = 0; kk < 4; ++kk) a[t][kk] = ldb8(ar + kk * 32);
    }

    // strip window: union of class ranges of rows i0..i0+127
    const int w0 = __builtin_amdgcn_readfirstlane(se[i0].x);
    const int w1 = __builtin_amdgcn_readfirstlane(se[i0 + 127].y);

    float hp[4][4], hn[4][4];                // dot-space: min-pos / max-neg
#pragma unroll
    for (int t = 0; t < 4; ++t)
#pragma unroll
        for (int m = 0; m < 4; ++m) { hp[t][m] = 1e30f; hn[t][m] = -1e30f; }

    // ---- staging: 8 gload_lds per wave per stage; LDS layout [col][chunk16B]
    // with source chunk ^= (col&7); read applies the same XOR (involution).
    const int colA  = lane >> 4;             // 0..3
    const int chunk = lane & 15;             // 16B chunk within a 256B col
    const int swz   = (wave * 4 + colA) & 7; // col&7 for this lane's cols
    const int soff  = (chunk ^ swz) << 3;    // source element offset

    auto STAGE = [&](int buf, int s) {
        const unsigned short* g0 = ebf + (size_t)(jbase + s * 128) * DIM;
#pragma unroll
        for (int l = 0; l < 8; ++l) {
            const int colbase = l * 16 + wave * 4;           // + colA = this lane's col
            gload_lds16(g0 + (size_t)(colbase + colA) * DIM + soff,
                        &bs[buf][colbase * DIM]);
        }
    };

    // ds_read constants: frag addr = colb[cg] + perm[kk] (conflict-free)
    int colb[4], perm[4];
#pragma unroll
    for (int cg = 0; cg < 4; ++cg) colb[cg] = (wc * 64 + cg * 16 + lr) * 256;
#pragma unroll
    for (int kk = 0; kk < 4; ++kk) perm[kk] = (((kk * 4 + lk)) ^ (lr & 7)) << 4;

    STAGE(0, 0);
    STAGE(1, 1);

    for (int s = 0; s < NST; ++s) {
        // counted wait: our stage-s 8 loads done; stage-s+1's 8 stay in flight
        if (s == NST - 1) { asm volatile("s_waitcnt vmcnt(0)" ::: "memory"); }
        else              { asm volatile("s_waitcnt vmcnt(8)" ::: "memory"); }
        __builtin_amdgcn_s_barrier();
        __builtin_amdgcn_sched_barrier(0);

        const int cur = s & 1;
        const char* bb = reinterpret_cast<const char*>(&bs[cur][0]);

        f32x4 acc[4][4];
#pragma unroll
        for (int t = 0; t < 4; ++t)
#pragma unroll
            for (int cg = 0; cg < 4; ++cg) acc[t][cg] = f32x4{0.f, 0.f, 0.f, 0.f};

#pragma unroll
        for (int kk = 0; kk < 4; ++kk) {
            bf16x8 b0 = *reinterpret_cast<const bf16x8*>(bb + colb[0] + perm[kk]);
            bf16x8 b1 = *reinterpret_cast<const bf16x8*>(bb + colb[1] + perm[kk]);
            bf16x8 b2 = *reinterpret_cast<const bf16x8*>(bb + colb[2] + perm[kk]);
            bf16x8 b3 = *reinterpret_cast<const bf16x8*>(bb + colb[3] + perm[kk]);
#pragma unroll
            for (int t = 0; t < 4; ++t) {
                acc[t][0] = __builtin_amdgcn_mfma_f32_16x16x32_bf16(a[t][kk], b0, acc[t][0], 0, 0, 0);
                acc[t][1] = __builtin_amdgcn_mfma_f32_16x16x32_bf16(a[t][kk], b1, acc[t][1], 0, 0, 0);
                acc[t][2] = __builtin_amdgcn_mfma_f32_16x16x32_bf16(a[t][kk], b2, acc[t][2], 0, 0, 0);
                acc[t][3] = __builtin_amdgcn_mfma_f32_16x16x32_bf16(a[t][kk], b3, acc[t][3], 0, 0, 0);
            }
        }

        const int j0w = jbase + s * 128 + wc * 64;     // this wave's 64 cols
        if (j0w + 64 <= w0 || j0w >= w1) {             // pure-negative (common)
#pragma unroll
            for (int t = 0; t < 4; ++t)
#pragma unroll
                for (int m = 0; m < 4; ++m)
                    hn[t][m] = fmaxf(fmaxf(fmaxf(fmaxf(acc[t][0][m], acc[t][1][m]),
                                                 fmaxf(acc[t][2][m], acc[t][3][m])),
                                           hn[t][m]), hn[t][m]);
        } else {                                       // mixed (near diagonal, rare)
#pragma unroll
            for (int t = 0; t < 4; ++t)
#pragma unroll
                for (int m = 0; m < 4; ++m) {
                    // volatile: keep these rare-path loads inside the branch
                    volatile const int2* vq = &se[i0 + wr * 64 + t * 16 + lk * 4 + m];
                    const int qs = vq->x, qe = vq->y;
#pragma unroll
                    for (int cg = 0; cg < 4; ++cg) {
                        const int jc = j0w + cg * 16 + lr;
                        const bool pos = (jc >= qs) && (jc < qe);
                        const float v = acc[t][cg][m];
                        hp[t][m] = pos ? fminf(hp[t][m], v) : hp[t][m];
                        hn[t][m] = pos ? hn[t][m] : fmaxf(hn[t][m], v);
                    }
                }
        }

        __builtin_amdgcn_s_barrier();                  // all waves done reading bs[cur]
        if (s + 2 < NST) STAGE(cur, s + 2);            // overwrite now safe
    }

    // reduce across the 16 lanes (lr) sharing accum rows, then pair waves (wc)
#pragma unroll
    for (int t = 0; t < 4; ++t)
#pragma unroll
        for (int m = 0; m < 4; ++m) {
            float p = hp[t][m], n = hn[t][m];
#pragma unroll
            for (int sft = 1; sft < 16; sft <<= 1) {
                p = fminf(p, __shfl_xor(p, sft));
                n = fmaxf(n, __shfl_xor(n, sft));
            }
            if (lr == 0) {
                int r = t * 16 + lk * 4 + m;
                hpL[wave][r] = p;
                hnL[wave][r] = n;
            }
        }
    __syncthreads();
    if (tid < 128) {                         // row = i0 + tid; waves wr*2, wr*2+1
        const int wrr = tid >> 6, r64 = tid & 63;
        float p = fminf(hpL[wrr * 2][r64], hpL[wrr * 2 + 1][r64]);
        float n = fmaxf(hnL[wrr * 2][r64], hnL[wrr * 2 + 1][r64]);
        atomicMin(&hp2[i0 + tid], encf(p));
        atomicMax(&hn2[i0 + tid], encf(n));
    }
    __syncthreads();                         // all this block's atomics performed

    // ---- folded finalize: last block to arrive reduces hp2/hn2 -> out[0] ----
    if (tid == 0) {
        __threadfence();                     // release our atomics
        amlast = (atomicAdd(done, 1) == NBLK - 1);
    }
    __syncthreads();
    if (!amlast) return;
    __threadfence();                         // acquire all blocks' atomics

    float sum = 0.f;
#pragma unroll
    for (int it = 0; it < BN / (256 * 4); ++it) {    // 8 iters, uint4 per thread
        int base = (it * 256 + tid) * 4;
        uint4 pv = *reinterpret_cast<const uint4*>(&hp2[base]);
        uint4 nv = *reinterpret_cast<const uint4*>(&hn2[base]);
        unsigned pa[4] = {pv.x, pv.y, pv.z, pv.w};
        unsigned na[4] = {nv.x, nv.y, nv.z, nv.w};
#pragma unroll
        for (int e = 0; e < 4; ++e) {
            float pd = decf(pa[e]);          // min dot over pos
            float nd = decf(na[e]);          // max dot over neg
            float hpv = sqrtf(fmaxf(2.0f - 2.0f * pd, 0.f));
            float hnv = sqrtf(fmaxf(2.0f - 2.0f * nd, 0.f));
            // relu(hp - hn + 0.5*(1+hp)) = relu(1.5*hp + 0.5 - hn)
            sum += fmaxf(fmaf(1.5f, hpv, 0.5f) - hnv, 0.f);
        }
    }
    float* red = &hpL[0][0];                 // reuse 256 floats of LDS
    red[tid] = sum;
    __syncthreads();
    for (int s2 = 128; s2 > 0; s2 >>= 1) {
        if (tid < s2) red[tid] += red[tid + s2];
        __syncthreads();
    }
    if (tid == 0) out[0] = red[0] * (1.0f / (float)BN);    // all rows valid
}

// ---------------------------------------------------------------- launch
extern "C" void kernel_launch(void* const* d_in, const int* in_sizes, int n_in,
                              void* d_out, int out_size, void* d_ws, size_t ws_size,
                              hipStream_t stream) {
    const float* emb    = (const float*)d_in[0];
    const int*   labels = (const int*)d_in[1];
    float* out = (float*)d_out;

    char* ws = (char*)d_ws;
    unsigned short* ebf = (unsigned short*)ws;                            // 2 MiB sorted bf16 E
    int2*     se   = (int2*)    (ws + 2u * 1024u * 1024u);                // 64 KiB class ranges
    unsigned* hp2  = (unsigned*)(ws + 2u * 1024u * 1024u + 64u * 1024u);  // 32 KiB
    unsigned* hn2  = (unsigned*)(ws + 2u * 1024u * 1024u + 96u * 1024u);  // 32 KiB
    int*      done = (int*)     (ws + 2u * 1024u * 1024u + 128u * 1024u); // 4 B

    hipLaunchKernelGGL(sort_norm, dim3(NCLS), dim3(256), 0, stream, emb, labels, ebf, se, hp2, hn2, done);
    hipLaunchKernelGGL(tri_main,  dim3(NBLK), dim3(256), 0, stream, ebf, se, hp2, hn2, done, out);
}